// Round 4
// baseline (107.865 us; speedup 1.0000x reference)
//
#include <hip/hip_runtime.h>

constexpr int Tn = 512;       // seq len
constexpr int Bn = 4096;      // batch
constexpr int CH = 32;        // timesteps per chunk
constexpr int NCH = Tn / CH;  // 16
constexpr int WPB = 8;        // waves per block (2 per SIMD)

// row_shr:1 within 16-lane rows: dst[i] = src[i-1]; lane0 of row keeps old.
__device__ __forceinline__ float dpp_shr1(float v) {
  return __int_as_float(__builtin_amdgcn_update_dpp(
      __float_as_int(v), __float_as_int(v), 0x111, 0xf, 0xf, false));
}
__device__ __forceinline__ float fast_sig(float x) {
  return __builtin_amdgcn_rcpf(1.0f + __expf(-x));
}
__device__ __forceinline__ float fast_tanh(float x) {
  // tanh(x) = 1 - 2/(exp(2x)+1); saturates to +/-1 on overflow/underflow
  return fmaf(-2.0f, __builtin_amdgcn_rcpf(1.0f + __expf(2.0f * x)), 1.0f);
}

// One LSTM pipeline tick. All lanes read their gate base from LDS:
// group leaders (lg==0) walk the projection tile (step=8 float4/tick),
// lanes 1..7 re-read their layer's bias entry (step=0, broadcast).
template <bool GATED>
__device__ __forceinline__ void tick(float& h, float& c, const float4*& p,
                                     int step, const float4 wih,
                                     const float4 whh, unsigned tau,
                                     unsigned lg) {
  const float4 base = *p;
  p += step;
  const float h_in = dpp_shr1(h);
  const float g0 = fmaf(h, whh.x, fmaf(h_in, wih.x, base.x));  // i
  const float g1 = fmaf(h, whh.y, fmaf(h_in, wih.y, base.y));  // f
  const float g2 = fmaf(h, whh.z, fmaf(h_in, wih.z, base.z));  // g~
  const float g3 = fmaf(h, whh.w, fmaf(h_in, wih.w, base.w));  // o
  const float ii = fast_sig(g0);
  const float ff = fast_sig(g1);
  const float gg = fast_tanh(g2);
  const float oo = fast_sig(g3);
  const float cn = fmaf(ff, c, ii * gg);
  const float hn = oo * fast_tanh(cn);
  if (GATED) {
    const bool act = (tau - lg) < (unsigned)Tn;  // unsigned wrap: tau<lg inactive
    c = act ? cn : c;
    h = act ? hn : h;
  } else {
    c = cn;
    h = hn;
  }
}

// Fused: layer-0 projection (streaming x) + 6-layer DPP-pipelined recurrence.
// 8 waves per block (2 per SIMD for latency hiding); each wave owns 8 batch
// elements (8 lanes each, lane=layer) and its own LDS slice. No barriers.
__global__ __launch_bounds__(WPB * 64) void lstm_fused_kernel(
    const float* __restrict__ x, const float* __restrict__ w_ih0,
    const float* __restrict__ w_ih_rest, const float* __restrict__ w_hh,
    const float* __restrict__ b_ih, const float* __restrict__ b_hh,
    float* __restrict__ out) {
  __shared__ __align__(16) float4 bufA[WPB][CH * 8];  // [wave][t_local*8+elem]
  __shared__ __align__(16) float4 bufB[WPB][CH * 8];
  __shared__ __align__(16) float4 biasT[WPB][8];      // per-layer bias, idx lg-1

  const int tid = threadIdx.x;
  const int wv = tid >> 6;        // wave in block
  const int ln = tid & 63;        // lane in wave
  const int bW = blockIdx.x * (WPB * 8) + wv * 8;  // wave's batch base
  // tick-phase roles
  const int ge = ln >> 3;         // batch element (group) 0..7
  const unsigned lg = ln & 7;     // pipeline lane = layer for lg<6
  const bool is0 = (lg == 0);
  // proj-phase roles
  const int ep = ln & 7;          // element
  const int t8p = ln >> 3;        // t sub-index 0..7

  // ---- per-lane recurrence weights ----
  const int l = (lg < 6) ? (int)lg : 5;
  float4 wih = make_float4(0.f, 0.f, 0.f, 0.f);
  float4 whh = make_float4(w_hh[l * 4 + 0], w_hh[l * 4 + 1], w_hh[l * 4 + 2],
                           w_hh[l * 4 + 3]);
  if (lg >= 1 && lg < 6)
    wih = make_float4(w_ih_rest[(l - 1) * 4 + 0], w_ih_rest[(l - 1) * 4 + 1],
                      w_ih_rest[(l - 1) * 4 + 2], w_ih_rest[(l - 1) * 4 + 3]);

  // ---- bias table (lanes 1..5 of each wave write their layer's bias) ----
  if (ln >= 1 && ln < 8) {
    float4 bv = make_float4(0.f, 0.f, 0.f, 0.f);
    if (ln <= 5)
      bv = make_float4(b_ih[ln * 4 + 0] + b_hh[ln * 4 + 0],
                       b_ih[ln * 4 + 1] + b_hh[ln * 4 + 1],
                       b_ih[ln * 4 + 2] + b_hh[ln * 4 + 2],
                       b_ih[ln * 4 + 3] + b_hh[ln * 4 + 3]);
    biasT[wv][ln - 1] = bv;
  }
  const float4* pbias = &biasT[wv][is0 ? 0 : (int)(lg - 1)];

  // ---- layer-0 projection weights (uniform -> scalar regs) ----
  float w[4][16], pb[4];
#pragma unroll
  for (int g = 0; g < 4; ++g) {
    pb[g] = b_ih[g] + b_hh[g];
#pragma unroll
    for (int d = 0; d < 16; ++d) w[g][d] = w_ih0[g * 16 + d];
  }

  const float4* x4 = (const float4*)x;
  // lane reads 64 B of x for (bW+ep, t = c*CH + t8p + 8k), k=0..3
  auto LOADC = [&](float4 xs[16], int cidx) {
    const size_t base = ((size_t)(bW + ep) * Tn + (size_t)cidx * CH + t8p) * 4;
#pragma unroll
    for (int k = 0; k < 4; ++k)
#pragma unroll
      for (int i = 0; i < 4; ++i) xs[k * 4 + i] = x4[base + (size_t)k * 32 + i];
  };
  auto PROJ = [&](const float4 xs[16], float4* dst) {
#pragma unroll
    for (int k = 0; k < 4; ++k) {
      float s0 = pb[0], s1 = pb[1], s2 = pb[2], s3 = pb[3];
#pragma unroll
      for (int i = 0; i < 4; ++i) {
        const float4 a = xs[k * 4 + i];
        s0 = fmaf(a.x, w[0][i * 4 + 0], s0); s0 = fmaf(a.y, w[0][i * 4 + 1], s0);
        s0 = fmaf(a.z, w[0][i * 4 + 2], s0); s0 = fmaf(a.w, w[0][i * 4 + 3], s0);
        s1 = fmaf(a.x, w[1][i * 4 + 0], s1); s1 = fmaf(a.y, w[1][i * 4 + 1], s1);
        s1 = fmaf(a.z, w[1][i * 4 + 2], s1); s1 = fmaf(a.w, w[1][i * 4 + 3], s1);
        s2 = fmaf(a.x, w[2][i * 4 + 0], s2); s2 = fmaf(a.y, w[2][i * 4 + 1], s2);
        s2 = fmaf(a.z, w[2][i * 4 + 2], s2); s2 = fmaf(a.w, w[2][i * 4 + 3], s2);
        s3 = fmaf(a.x, w[3][i * 4 + 0], s3); s3 = fmaf(a.y, w[3][i * 4 + 1], s3);
        s3 = fmaf(a.z, w[3][i * 4 + 2], s3); s3 = fmaf(a.w, w[3][i * 4 + 3], s3);
      }
      dst[ln + 64 * k] = make_float4(s0, s1, s2, s3);  // [(t8p+8k)*8 + ep]
    }
  };

  float h = 0.f, c = 0.f;
  float4 xs[16];

  // ---- prologue: chunk 0 projected, chunk 1 in flight ----
  LOADC(xs, 0);
  PROJ(xs, bufA[wv]);
  LOADC(xs, 1);

  // ---- chunk 0 ticks: first 8 gated (pipeline fill), rest clean ----
  {
    const float4* p = is0 ? (bufA[wv] + ge) : pbias;
    const int step = is0 ? 8 : 0;
#pragma unroll
    for (unsigned k = 0; k < 8; ++k)
      tick<true>(h, c, p, step, wih, whh, k, lg);
#pragma unroll 8
    for (int k = 8; k < CH; ++k)
      tick<false>(h, c, p, step, wih, whh, 0u, 0u);
    PROJ(xs, bufB[wv]);   // chunk 1 -> bufB
    LOADC(xs, 2);
  }

  // ---- main loop: chunks 1..15 ----
#pragma unroll 1
  for (int j = 1; j < NCH; ++j) {
    float4* bufj = (j & 1) ? bufB[wv] : bufA[wv];
    const float4* p = is0 ? (bufj + ge) : pbias;
    const int step = is0 ? 8 : 0;
#pragma unroll 8
    for (int k = 0; k < CH; ++k)
      tick<false>(h, c, p, step, wih, whh, 0u, 0u);
    if (j < NCH - 1) PROJ(xs, (j & 1) ? bufA[wv] : bufB[wv]);  // chunk j+1
    if (j < NCH - 2) LOADC(xs, j + 2);
  }

  // ---- tail: 5 gated ticks (tau = 512..516); leaders inactive ----
  {
    const float4* p = is0 ? (bufA[wv] + ge) : pbias;  // leader value unused
#pragma unroll
    for (unsigned k = 0; k < 5; ++k)
      tick<true>(h, c, p, 0, wih, whh, 512u + k, lg);
  }

  if (lg == 5) out[bW + ge] = h;  // H=1: hidden channel 0 == h
}

extern "C" void kernel_launch(void* const* d_in, const int* in_sizes, int n_in,
                              void* d_out, int out_size, void* d_ws, size_t ws_size,
                              hipStream_t stream) {
  (void)in_sizes; (void)n_in; (void)out_size; (void)d_ws; (void)ws_size;
  const float* x         = (const float*)d_in[0];
  const float* w_ih0     = (const float*)d_in[1];
  const float* w_ih_rest = (const float*)d_in[2];
  const float* w_hh      = (const float*)d_in[3];
  const float* b_ih      = (const float*)d_in[4];
  const float* b_hh      = (const float*)d_in[5];
  float* out = (float*)d_out;

  lstm_fused_kernel<<<Bn * 8 / (WPB * 64), WPB * 64, 0, stream>>>(
      x, w_ih0, w_ih_rest, w_hh, b_ih, b_hh, out);
}

// Round 5
// 61.657 us; speedup vs baseline: 1.7494x; 1.7494x over previous
//
#include <hip/hip_runtime.h>

constexpr int Tn = 512;       // seq len
constexpr int Bn = 4096;      // batch
constexpr int CH = 32;        // timesteps per chunk
constexpr int NCH = Tn / CH;  // 16

// Gate pre-activations are computed PRE-SCALED by folding these into the
// weights/biases: i,f,o gates by -log2e (sigmoid), g gate by +2*log2e (tanh).
constexpr float NL2E = -1.44269504088896340736f;
constexpr float P2L2E = 2.88539008177792681472f;

#if defined(__has_builtin)
#if __has_builtin(__builtin_amdgcn_exp2f)
#define EXP2F(x) __builtin_amdgcn_exp2f(x)
#else
#define EXP2F(x) exp2f(x)
#endif
#else
#define EXP2F(x) exp2f(x)
#endif

// row_shr:1 within 16-lane rows: dst[i] = src[i-1]; lane0 of row keeps old.
__device__ __forceinline__ float dpp_shr1(float v) {
  return __int_as_float(__builtin_amdgcn_update_dpp(
      __float_as_int(v), __float_as_int(v), 0x111, 0xf, 0xf, false));
}
// xs = -log2e * x   -> sigmoid(x) = 1/(1+2^xs)
__device__ __forceinline__ float sig_p(float xs) {
  return __builtin_amdgcn_rcpf(1.0f + EXP2F(xs));
}
// xt = 2*log2e * x  -> tanh(x) = 1 - 2/(1+2^xt)
__device__ __forceinline__ float tanh_p(float xt) {
  return fmaf(-2.0f, __builtin_amdgcn_rcpf(1.0f + EXP2F(xt)), 1.0f);
}
// unscaled tanh (for cell state)
__device__ __forceinline__ float tanh_u(float x) {
  return fmaf(-2.0f, __builtin_amdgcn_rcpf(1.0f + EXP2F(P2L2E * x)), 1.0f);
}

// One LSTM pipeline tick; gate base `pre` already in registers (pre-scaled).
template <bool GATED>
__device__ __forceinline__ void tick(float& h, float& c, const float4 pre,
                                     const float4 wih, const float4 whh,
                                     unsigned tau, unsigned lg) {
  const float h_in = dpp_shr1(h);
  const float g0 = fmaf(h, whh.x, fmaf(h_in, wih.x, pre.x));  // i (scaled)
  const float g1 = fmaf(h, whh.y, fmaf(h_in, wih.y, pre.y));  // f (scaled)
  const float g2 = fmaf(h, whh.z, fmaf(h_in, wih.z, pre.z));  // g (scaled)
  const float g3 = fmaf(h, whh.w, fmaf(h_in, wih.w, pre.w));  // o (scaled)
  const float ii = sig_p(g0);
  const float ff = sig_p(g1);
  const float gg = tanh_p(g2);
  const float oo = sig_p(g3);
  const float cn = fmaf(ff, c, ii * gg);
  const float hn = oo * tanh_u(cn);
  if (GATED) {
    const bool act = (tau - lg) < (unsigned)Tn;  // unsigned wrap: tau<lg inactive
    c = act ? cn : c;
    h = act ? hn : h;
  } else {
    c = cn;
    h = hn;
  }
}

// Fused: layer-0 projection (streaming x) + 6-layer DPP-pipelined recurrence.
// 1 wave per block, 8 batch elements per wave (8 lanes each, lane=layer).
__global__ __launch_bounds__(64, 1) void lstm_fused_kernel(
    const float* __restrict__ x, const float* __restrict__ w_ih0,
    const float* __restrict__ w_ih_rest, const float* __restrict__ w_hh,
    const float* __restrict__ b_ih, const float* __restrict__ b_hh,
    float* __restrict__ out) {
  __shared__ __align__(16) float4 bufA[CH * 8];  // [t_local][elem]
  __shared__ __align__(16) float4 bufB[CH * 8];

  const int ln = threadIdx.x;
  const int bW = blockIdx.x * 8;  // wave's batch base
  // tick-phase roles
  const int ge = ln >> 3;         // batch element (group) 0..7
  const unsigned lg = ln & 7;     // pipeline lane = layer for lg<6
  const bool is0 = (lg == 0);
  // proj-phase roles
  const int ep = ln & 7;          // element
  const int t8p = ln >> 3;        // t sub-index 0..7

  // ---- per-lane recurrence weights (pre-scaled) ----
  const int l = (lg < 6) ? (int)lg : 5;
  float4 whh = make_float4(NL2E * w_hh[l * 4 + 0], NL2E * w_hh[l * 4 + 1],
                           P2L2E * w_hh[l * 4 + 2], NL2E * w_hh[l * 4 + 3]);
  float4 wih = make_float4(0.f, 0.f, 0.f, 0.f);
  float4 bz = make_float4(0.f, 0.f, 0.f, 0.f);  // non-leader gate bias (scaled)
  if (lg >= 1 && lg < 6) {
    wih = make_float4(NL2E * w_ih_rest[(l - 1) * 4 + 0],
                      NL2E * w_ih_rest[(l - 1) * 4 + 1],
                      P2L2E * w_ih_rest[(l - 1) * 4 + 2],
                      NL2E * w_ih_rest[(l - 1) * 4 + 3]);
    bz = make_float4(NL2E * (b_ih[lg * 4 + 0] + b_hh[lg * 4 + 0]),
                     NL2E * (b_ih[lg * 4 + 1] + b_hh[lg * 4 + 1]),
                     P2L2E * (b_ih[lg * 4 + 2] + b_hh[lg * 4 + 2]),
                     NL2E * (b_ih[lg * 4 + 3] + b_hh[lg * 4 + 3]));
  }
  if (lg >= 6) whh = make_float4(0.f, 0.f, 0.f, 0.f);  // inert lanes
  const float selm = is0 ? 1.0f : 0.0f;  // fma-mask: pre = proj*selm + bz

  // ---- layer-0 projection weights (uniform -> scalar regs), pre-scaled ----
  float w[4][16], pb[4];
  {
    const float sc[4] = {NL2E, NL2E, P2L2E, NL2E};
#pragma unroll
    for (int g = 0; g < 4; ++g) {
      pb[g] = sc[g] * (b_ih[g] + b_hh[g]);
#pragma unroll
      for (int d = 0; d < 16; ++d) w[g][d] = sc[g] * w_ih0[g * 16 + d];
    }
  }

  const float4* x4 = (const float4*)x;
  float4 xs[16];
  float h = 0.f, c = 0.f;

  // lane reads 64 B of x for (bW+ep, t = c*CH + t8p + 8k), k=0..3
  auto LOADC = [&](int cidx) {
    const size_t base = ((size_t)(bW + ep) * Tn + (size_t)cidx * CH + t8p) * 4;
#pragma unroll
    for (int k = 0; k < 4; ++k)
#pragma unroll
      for (int i = 0; i < 4; ++i) xs[k * 4 + i] = x4[base + (size_t)k * 32 + i];
  };
  // projection quarter k: t = t8p + 8k of the chunk in xs
  auto PROJq = [&](float4* dst, int k) {
    float s0 = pb[0], s1 = pb[1], s2 = pb[2], s3 = pb[3];
#pragma unroll
    for (int i = 0; i < 4; ++i) {
      const float4 a = xs[k * 4 + i];
      s0 = fmaf(a.x, w[0][i * 4 + 0], s0); s0 = fmaf(a.y, w[0][i * 4 + 1], s0);
      s0 = fmaf(a.z, w[0][i * 4 + 2], s0); s0 = fmaf(a.w, w[0][i * 4 + 3], s0);
      s1 = fmaf(a.x, w[1][i * 4 + 0], s1); s1 = fmaf(a.y, w[1][i * 4 + 1], s1);
      s1 = fmaf(a.z, w[1][i * 4 + 2], s1); s1 = fmaf(a.w, w[1][i * 4 + 3], s1);
      s2 = fmaf(a.x, w[2][i * 4 + 0], s2); s2 = fmaf(a.y, w[2][i * 4 + 1], s2);
      s2 = fmaf(a.z, w[2][i * 4 + 2], s2); s2 = fmaf(a.w, w[2][i * 4 + 3], s2);
      s3 = fmaf(a.x, w[3][i * 4 + 0], s3); s3 = fmaf(a.y, w[3][i * 4 + 1], s3);
      s3 = fmaf(a.z, w[3][i * 4 + 2], s3); s3 = fmaf(a.w, w[3][i * 4 + 3], s3);
    }
    dst[ln + 64 * k] = make_float4(s0, s1, s2, s3);  // [(t8p+8k)*8 + ep]
  };
  // one 8-tick block: bulk LDS->reg (broadcast reads), fma-mask, 8 clean ticks
  auto blockT = [&](const float4* bufc, int jb) {
    float4 pr[8];
#pragma unroll
    for (int k = 0; k < 8; ++k) pr[k] = bufc[jb * 64 + k * 8 + ge];
#pragma unroll
    for (int k = 0; k < 8; ++k) {
      pr[k].x = fmaf(pr[k].x, selm, bz.x);
      pr[k].y = fmaf(pr[k].y, selm, bz.y);
      pr[k].z = fmaf(pr[k].z, selm, bz.z);
      pr[k].w = fmaf(pr[k].w, selm, bz.w);
    }
#pragma unroll
    for (int k = 0; k < 8; ++k) tick<false>(h, c, pr[k], wih, whh, 0u, 0u);
  };
  // gated variant (pipeline fill)
  auto blockTg = [&](const float4* bufc, int jb, unsigned tau0) {
    float4 pr[8];
#pragma unroll
    for (int k = 0; k < 8; ++k) pr[k] = bufc[jb * 64 + k * 8 + ge];
#pragma unroll
    for (int k = 0; k < 8; ++k) {
      pr[k].x = fmaf(pr[k].x, selm, bz.x);
      pr[k].y = fmaf(pr[k].y, selm, bz.y);
      pr[k].z = fmaf(pr[k].z, selm, bz.z);
      pr[k].w = fmaf(pr[k].w, selm, bz.w);
    }
#pragma unroll
    for (int k = 0; k < 8; ++k)
      tick<true>(h, c, pr[k], wih, whh, tau0 + (unsigned)k, lg);
  };

  // ---- prologue: chunk 0 projected into bufA, chunk 1 x in regs ----
  LOADC(0);
#pragma unroll
  for (int k = 0; k < 4; ++k) PROJq(bufA, k);
  LOADC(1);

  // ---- chunk 0: block 0 gated (pipeline fill), 1..3 clean ----
  blockTg(bufA, 0, 0u);
  blockT(bufA, 1);
  PROJq(bufB, 0); PROJq(bufB, 1);
  blockT(bufA, 2);
  PROJq(bufB, 2); PROJq(bufB, 3);
  blockT(bufA, 3);
  LOADC(2);

  // ---- chunks 1..15 ----
#pragma unroll 1
  for (int j = 1; j < NCH; ++j) {
    const float4* bc = (j & 1) ? bufB : bufA;
    float4* bn = (j & 1) ? bufA : bufB;
    blockT(bc, 0);
    blockT(bc, 1);
    if (j < NCH - 1) { PROJq(bn, 0); PROJq(bn, 1); }
    blockT(bc, 2);
    if (j < NCH - 1) { PROJq(bn, 2); PROJq(bn, 3); }
    blockT(bc, 3);
    if (j < NCH - 2) LOADC(j + 2);
  }

  // ---- tail: 5 gated ticks (tau=512..516); leaders inactive, pre=bz ----
#pragma unroll
  for (unsigned k = 0; k < 5; ++k)
    tick<true>(h, c, bz, wih, whh, 512u + k, lg);

  if (lg == 5) out[bW + ge] = h;  // H=1: hidden channel 0 == h
}

extern "C" void kernel_launch(void* const* d_in, const int* in_sizes, int n_in,
                              void* d_out, int out_size, void* d_ws, size_t ws_size,
                              hipStream_t stream) {
  (void)in_sizes; (void)n_in; (void)out_size; (void)d_ws; (void)ws_size;
  const float* x         = (const float*)d_in[0];
  const float* w_ih0     = (const float*)d_in[1];
  const float* w_ih_rest = (const float*)d_in[2];
  const float* w_hh      = (const float*)d_in[3];
  const float* b_ih      = (const float*)d_in[4];
  const float* b_hh      = (const float*)d_in[5];
  float* out = (float*)d_out;

  lstm_fused_kernel<<<Bn / 8, 64, 0, stream>>>(x, w_ih0, w_ih_rest, w_hh,
                                               b_ih, b_hh, out);
}